// Round 14
// baseline (4240.944 us; speedup 1.0000x reference)
//
#include <hip/hip_runtime.h>
#include <math.h>

#define BATCH 10
#define HID 128
#define OUT 7
#define MAXLEN 2048
#define NG 512
#define NT 1024
#define LOGBUF 16
#define OFF_STATE ((size_t)BATCH * MAXLEN * OUT)

typedef _Float16 half8 __attribute__((ext_vector_type(8)));
typedef float float4v __attribute__((ext_vector_type(4)));

__device__ __forceinline__ float sigm_(float x) { return 1.0f / (1.0f + __expf(-x)); }
__device__ __forceinline__ float tanh_(float x) { return 1.0f - 2.0f / (1.0f + __expf(2.0f * x)); }

// store h into the A-fragment-layout LDS staging (hi/lo f16 split)
__device__ __forceinline__ void h_store(_Float16 (*afr)[4][64][8], int m, int i, float h) {
    _Float16 hh = (_Float16)h;
    _Float16 hl = (_Float16)(h - (float)hh);
    const int kc = i >> 5, q = (i >> 3) & 3, j = i & 7;
    afr[0][kc][q * 16 + m][j] = hh;
    afr[1][kc][q * 16 + m][j] = hl;
}

__global__
__attribute__((amdgpu_flat_work_group_size(NT, NT), amdgpu_waves_per_eu(4, 4)))
void decoder_rnn_kernel(const float* __restrict__ h0,
                        const float* __restrict__ c0,
                        const float* __restrict__ tonehot,   // (MAXLEN+1, 1, OUT)
                        const void*  __restrict__ tf_raw,    // bool mask, int8 or int32
                        const float* __restrict__ Wih,       // (4H, OUT)
                        const float* __restrict__ Whh,       // (4H, H)
                        const float* __restrict__ bih,
                        const float* __restrict__ bhh,
                        const float* __restrict__ Wout,      // (OUT, H)
                        const float* __restrict__ bout,
                        float* __restrict__ out)
{
    // ALL 10 chains in ONE block: mfma M-rows = chains (rows 10-15 zero).
    __shared__ __align__(16) _Float16 afr[2][4][64][8];  // [split][kchunk][lane][j]
    __shared__ float gates_lds[BATCH][NG];               // mfma D: pre-bias gates
    __shared__ float wih_eff[OUT * NG];                  // Wih^T + bias, [x][g]
    __shared__ float ring[BATCH][LOGBUF][OUT];           // raw biased logits
    __shared__ float lp[2][BATCH][8];                    // logits K-partials
    __shared__ float bout_lds[8];
    __shared__ unsigned char tgt8[MAXLEN];
    __shared__ unsigned char tf8[MAXLEN];
    __shared__ int xsel_sh[BATCH];
    __shared__ int tf_byte_mode;

    const int t    = threadIdx.x;
    const int lane = t & 63;
    const int wv   = t >> 6;       // wave 0..15 -> gate tiles 2wv, 2wv+1
    const int quad = lane >> 4;
    const int mrow = lane & 15;

    // ---- B-fragments (weights) in registers, f16 hi/lo split ----
    // B[k][n]: lane holds n=mrow (+tile*16), k = kchunk*32 + quad*8 + j
    half8 Bhi[2][4], Blo[2][4];
    {
        const int g0 = wv * 32 + mrow;
        const int g1 = g0 + 16;
        #pragma unroll
        for (int kc = 0; kc < 4; kc++) {
            const int kb = kc * 32 + quad * 8;
            const float* p0 = Whh + (size_t)g0 * HID + kb;
            const float* p1 = Whh + (size_t)g1 * HID + kb;
            #pragma unroll
            for (int j = 0; j < 8; j++) {
                float w0 = p0[j];
                _Float16 h0_ = (_Float16)w0;
                Bhi[0][kc][j] = h0_;
                Blo[0][kc][j] = (_Float16)(w0 - (float)h0_);
                float w1 = p1[j];
                _Float16 h1_ = (_Float16)w1;
                Bhi[1][kc][j] = h1_;
                Blo[1][kc][j] = (_Float16)(w1 - (float)h1_);
            }
        }
    }
    // logits tile (Wout rows as cols 512..518), K-split: wave0 kc 0-1, wave1 kc 2-3
    half8 BLhi[2], BLlo[2];
    {
        #pragma unroll
        for (int c = 0; c < 2; c++)
            #pragma unroll
            for (int j = 0; j < 8; j++) { BLhi[c][j] = (_Float16)0; BLlo[c][j] = (_Float16)0; }
        if (wv < 2 && mrow < OUT) {
            #pragma unroll
            for (int c = 0; c < 2; c++) {
                const int kb = (wv * 2 + c) * 32 + quad * 8;
                const float* p = Wout + (size_t)mrow * HID + kb;
                #pragma unroll
                for (int j = 0; j < 8; j++) {
                    float w = p[j];
                    _Float16 hh = (_Float16)w;
                    BLhi[c][j] = hh;
                    BLlo[c][j] = (_Float16)(w - (float)hh);
                }
            }
        }
    }

    // ---- LDS setup ----
    for (int i = t; i < 2 * 4 * 64 * 8 / 2; i += NT) ((int*)afr)[i] = 0;
    for (int idx = t; idx < OUT * NG; idx += NT) {
        int x = idx >> 9, g = idx & (NG - 1);
        wih_eff[idx] = Wih[g * OUT + x] + bih[g] + bhh[g];
    }
    if (t < 8) bout_lds[t] = (t < OUT) ? bout[t] : 0.0f;
    if (t < BATCH) xsel_sh[t] = OUT - 1;          // x0 one-hot at OUT-1
    for (int s = t; s < MAXLEN; s += NT) {
        const float* row = tonehot + (size_t)(s + 1) * OUT;
        int idx = 0;
        #pragma unroll
        for (int j = 0; j < OUT; j++) if (row[j] > 0.5f) idx = j;
        tgt8[s] = (unsigned char)idx;
    }
    if (t == 0) tf_byte_mode = 0;
    __syncthreads();
    {   // tf_mask layout detection (int8 bool vs int32) — R13-proven
        const unsigned char* tb = (const unsigned char*)tf_raw;
        int mis = 0;
        for (int p = t; p < MAXLEN; p += NT)
            if ((p & 3) && tb[p]) mis = 1;
        if (mis) atomicOr(&tf_byte_mode, 1);
    }
    // ---- state init (afr zeroed above; write rows 0..9) ----
    float c1, hv1, c2 = 0.f, hv2 = 0.f;
    {
        const int m = t >> 7, i = t & 127;
        hv1 = h0[m * HID + i];
        c1  = c0[m * HID + i];
        h_store(afr, m, i, hv1);
    }
    if (t < 256) {
        const int m = 8 + (t >> 7), i = t & 127;
        hv2 = h0[m * HID + i];
        c2  = c0[m * HID + i];
        h_store(afr, m, i, hv2);
    }
    __syncthreads();
    if (tf_byte_mode) {
        const unsigned char* tb = (const unsigned char*)tf_raw;
        for (int s = t; s < MAXLEN; s += NT) tf8[s] = (tb[s] != 0);
    } else {
        const int* ti = (const int*)tf_raw;
        for (int s = t; s < MAXLEN; s += NT) tf8[s] = (ti[s] != 0);
    }
    __syncthreads();

    for (int s = 0; s < MAXLEN; s++) {
        // ---- MFMA phase: gates(s) for all 10 chains + logits(s-1) ----
        float4v acc0 = {0.f, 0.f, 0.f, 0.f};
        float4v acc1 = {0.f, 0.f, 0.f, 0.f};
        float4v lacc = {0.f, 0.f, 0.f, 0.f};
        #pragma unroll
        for (int kc = 0; kc < 4; kc++) {
            const half8 ahi = *(const half8*)&afr[0][kc][lane][0];
            const half8 alo = *(const half8*)&afr[1][kc][lane][0];
            acc0 = __builtin_amdgcn_mfma_f32_16x16x32_f16(ahi, Bhi[0][kc], acc0, 0, 0, 0);
            acc0 = __builtin_amdgcn_mfma_f32_16x16x32_f16(ahi, Blo[0][kc], acc0, 0, 0, 0);
            acc0 = __builtin_amdgcn_mfma_f32_16x16x32_f16(alo, Bhi[0][kc], acc0, 0, 0, 0);
            acc1 = __builtin_amdgcn_mfma_f32_16x16x32_f16(ahi, Bhi[1][kc], acc1, 0, 0, 0);
            acc1 = __builtin_amdgcn_mfma_f32_16x16x32_f16(ahi, Blo[1][kc], acc1, 0, 0, 0);
            acc1 = __builtin_amdgcn_mfma_f32_16x16x32_f16(alo, Bhi[1][kc], acc1, 0, 0, 0);
            if (wv < 2 && (kc >> 1) == wv) {
                const int c = kc & 1;
                lacc = __builtin_amdgcn_mfma_f32_16x16x32_f16(ahi, BLhi[c], lacc, 0, 0, 0);
                lacc = __builtin_amdgcn_mfma_f32_16x16x32_f16(ahi, BLlo[c], lacc, 0, 0, 0);
                lacc = __builtin_amdgcn_mfma_f32_16x16x32_f16(alo, BLhi[c], lacc, 0, 0, 0);
            }
        }
        // C/D layout: col = lane&15, row = quad*4 + reg (row = chain)
        #pragma unroll
        for (int r = 0; r < 4; r++) {
            const int row = quad * 4 + r;
            if (row < BATCH) {
                gates_lds[row][wv * 32 + mrow]      = acc0[r];
                gates_lds[row][wv * 32 + 16 + mrow] = acc1[r];
            }
        }
        if (wv < 2) {
            #pragma unroll
            for (int r = 0; r < 4; r++) {
                const int row = quad * 4 + r;
                if (row < BATCH && mrow < 8) lp[wv][row][mrow] = lacc[r];
            }
        }
        __syncthreads();   // A: gates + logit partials ready

        // ---- argmax + xsel per chain (thread t = chain) ----
        if (s > 0 && t < BATCH) {
            float lg[OUT];
            #pragma unroll
            for (int j = 0; j < OUT; j++) lg[j] = lp[0][t][j] + lp[1][t][j] + bout_lds[j];
            float bv = lg[0]; int bi = 0;
            #pragma unroll
            for (int j = 1; j < OUT; j++) if (lg[j] > bv) { bv = lg[j]; bi = j; }  // first-index tiebreak
            xsel_sh[t] = tf8[s - 1] ? (int)tgt8[s - 1] : bi;
            const int slot = (s - 1) & (LOGBUF - 1);
            #pragma unroll
            for (int j = 0; j < OUT; j++) ring[t][slot][j] = lg[j];
        }
        __syncthreads();   // A2: xsel + ring slot ready

        // ---- bulk flush with deferred log-softmax (every 16 steps) ----
        if ((s & (LOGBUF - 1)) == 0 && s > 0) {
            const int base = s - LOGBUF;
            for (int i = t; i < BATCH * LOGBUF; i += NT) {
                const int m = i >> 4, st = i & 15;
                float v[OUT];
                #pragma unroll
                for (int j = 0; j < OUT; j++) v[j] = ring[m][st][j];
                float mx = v[0];
                #pragma unroll
                for (int j = 1; j < OUT; j++) mx = fmaxf(mx, v[j]);
                float sum = 0.f;
                #pragma unroll
                for (int j = 0; j < OUT; j++) sum += __expf(v[j] - mx);
                const float lse = mx + __logf(sum);
                float* dst = out + (size_t)m * MAXLEN * OUT + (size_t)(base + st) * OUT;
                #pragma unroll
                for (int j = 0; j < OUT; j++) dst[j] = v[j] - lse;
            }
        }

        // ---- pointwise: 1280 units on 1024 threads ----
        {
            const int m = t >> 7, i = t & 127;
            const int xo = xsel_sh[m] * NG;
            float ri = gates_lds[m][i]           + wih_eff[xo + i];
            float rf = gates_lds[m][HID + i]     + wih_eff[xo + HID + i];
            float rg = gates_lds[m][2 * HID + i] + wih_eff[xo + 2 * HID + i];
            float ro = gates_lds[m][3 * HID + i] + wih_eff[xo + 3 * HID + i];
            float cn = sigm_(rf) * c1 + sigm_(ri) * tanh_(rg);
            c1 = cn;
            hv1 = sigm_(ro) * tanh_(cn);
            h_store(afr, m, i, hv1);
        }
        if (t < 256) {
            const int m = 8 + (t >> 7), i = t & 127;
            const int xo = xsel_sh[m] * NG;
            float ri = gates_lds[m][i]           + wih_eff[xo + i];
            float rf = gates_lds[m][HID + i]     + wih_eff[xo + HID + i];
            float rg = gates_lds[m][2 * HID + i] + wih_eff[xo + 2 * HID + i];
            float ro = gates_lds[m][3 * HID + i] + wih_eff[xo + 3 * HID + i];
            float cn = sigm_(rf) * c2 + sigm_(ri) * tanh_(rg);
            c2 = cn;
            hv2 = sigm_(ro) * tanh_(cn);
            h_store(afr, m, i, hv2);
        }
        __syncthreads();   // C: h(s+1) staged in afr
    }

    // ---- epilogue: logits for step 2047 from h_2048 ----
    if (wv < 2) {
        float4v lacc = {0.f, 0.f, 0.f, 0.f};
        #pragma unroll
        for (int c = 0; c < 2; c++) {
            const int kc = wv * 2 + c;
            const half8 ahi = *(const half8*)&afr[0][kc][lane][0];
            const half8 alo = *(const half8*)&afr[1][kc][lane][0];
            lacc = __builtin_amdgcn_mfma_f32_16x16x32_f16(ahi, BLhi[c], lacc, 0, 0, 0);
            lacc = __builtin_amdgcn_mfma_f32_16x16x32_f16(ahi, BLlo[c], lacc, 0, 0, 0);
            lacc = __builtin_amdgcn_mfma_f32_16x16x32_f16(alo, BLhi[c], lacc, 0, 0, 0);
        }
        #pragma unroll
        for (int r = 0; r < 4; r++) {
            const int row = quad * 4 + r;
            if (row < BATCH && mrow < 8) lp[wv][row][mrow] = lacc[r];
        }
    }
    __syncthreads();
    if (t < BATCH) {
        const int slot = (MAXLEN - 1) & (LOGBUF - 1);
        #pragma unroll
        for (int j = 0; j < OUT; j++)
            ring[t][slot][j] = lp[0][t][j] + lp[1][t][j] + bout_lds[j];
    }
    __syncthreads();
    {   // final flush: steps 2032..2047
        const int base = MAXLEN - LOGBUF;
        for (int i = t; i < BATCH * LOGBUF; i += NT) {
            const int m = i >> 4, st = i & 15;
            float v[OUT];
            #pragma unroll
            for (int j = 0; j < OUT; j++) v[j] = ring[m][st][j];
            float mx = v[0];
            #pragma unroll
            for (int j = 1; j < OUT; j++) mx = fmaxf(mx, v[j]);
            float sum = 0.f;
            #pragma unroll
            for (int j = 0; j < OUT; j++) sum += __expf(v[j] - mx);
            const float lse = mx + __logf(sum);
            float* dst = out + (size_t)m * MAXLEN * OUT + (size_t)(base + st) * OUT;
            #pragma unroll
            for (int j = 0; j < OUT; j++) dst[j] = v[j] - lse;
        }
    }
    // final states
    {
        const int m = t >> 7, i = t & 127;
        out[OFF_STATE + m * HID + i] = hv1;
        out[OFF_STATE + BATCH * HID + m * HID + i] = c1;
    }
    if (t < 256) {
        const int m = 8 + (t >> 7), i = t & 127;
        out[OFF_STATE + m * HID + i] = hv2;
        out[OFF_STATE + BATCH * HID + m * HID + i] = c2;
    }
}

extern "C" void kernel_launch(void* const* d_in, const int* in_sizes, int n_in,
                              void* d_out, int out_size, void* d_ws, size_t ws_size,
                              hipStream_t stream) {
    const float* h0    = (const float*)d_in[0];
    const float* c0    = (const float*)d_in[1];
    const float* toh   = (const float*)d_in[2];
    const void*  tfm   = (const void*) d_in[3];
    const float* Wih   = (const float*)d_in[4];
    const float* Whh   = (const float*)d_in[5];
    const float* bih   = (const float*)d_in[6];
    const float* bhh   = (const float*)d_in[7];
    const float* Wout  = (const float*)d_in[8];
    const float* bout  = (const float*)d_in[9];
    float* out = (float*)d_out;

    decoder_rnn_kernel<<<dim3(1), dim3(NT), 0, stream>>>(
        h0, c0, toh, tfm, Wih, Whh, bih, bhh, Wout, bout, out);
}

// Round 15
// 2958.986 us; speedup vs baseline: 1.4332x; 1.4332x over previous
//
#include <hip/hip_runtime.h>
#include <math.h>

#define BATCH 10
#define HID 128
#define OUT 7
#define MAXLEN 2048
#define NG 512
#define NT 1024
#define LOGBUF 256
#define OFF_STATE ((size_t)BATCH * MAXLEN * OUT)

typedef _Float16 half8 __attribute__((ext_vector_type(8)));
typedef float float4v __attribute__((ext_vector_type(4)));

__device__ __forceinline__ float sigm_(float x) { return 1.0f / (1.0f + __expf(-x)); }
__device__ __forceinline__ float tanh_(float x) { return 1.0f - 2.0f / (1.0f + __expf(2.0f * x)); }

__global__
__attribute__((amdgpu_flat_work_group_size(NT, NT), amdgpu_waves_per_eu(4, 4)))
void decoder_rnn_kernel(const float* __restrict__ h0,
                        const float* __restrict__ c0,
                        const float* __restrict__ tonehot,   // (MAXLEN+1, 1, OUT)
                        const void*  __restrict__ tf_raw,    // bool mask, int8 or int32
                        const float* __restrict__ Wih,       // (4H, OUT)
                        const float* __restrict__ Whh,       // (4H, H)
                        const float* __restrict__ bih,
                        const float* __restrict__ bhh,
                        const float* __restrict__ Wout,      // (OUT, H)
                        const float* __restrict__ bout,
                        float* __restrict__ out)
{
    // 1 chain per block (10 CUs). A-fragment trick: all 16 A-rows = h, so the
    // staging is a 512B h16 array read by 16B broadcast, and any D-row works.
    __shared__ __align__(16) _Float16 h16s[2][HID];      // h hi/lo f16 split
    __shared__ float gates_lds[NG];                      // MFMA D: pre-bias gates
    __shared__ float wih_eff[OUT * NG];                  // Wih^T + bias, [x][g]
    __shared__ float ring[LOGBUF][OUT];                  // raw biased logits
    __shared__ float lp[2][8];                           // logits K-partials
    __shared__ float bout_lds[8];
    __shared__ unsigned char tgt8[MAXLEN];
    __shared__ unsigned char tf8[MAXLEN];
    __shared__ int xsel_sh;
    __shared__ int tf_byte_mode;

    const int t    = threadIdx.x;
    const int lane = t & 63;
    const int wv   = t >> 6;       // wave 0..15 -> gate cols wv*32 .. wv*32+31
    const int quad = lane >> 4;
    const int mrow = lane & 15;
    const int b    = blockIdx.x;

    // ---- B-fragments (W_hh) in registers, f16 hi/lo split (R14-verified) ----
    half8 Bhi[2][4], Blo[2][4];
    {
        const int g0 = wv * 32 + mrow;
        const int g1 = g0 + 16;
        #pragma unroll
        for (int kc = 0; kc < 4; kc++) {
            const int kb = kc * 32 + quad * 8;
            const float* p0 = Whh + (size_t)g0 * HID + kb;
            const float* p1 = Whh + (size_t)g1 * HID + kb;
            #pragma unroll
            for (int j = 0; j < 8; j++) {
                float w0 = p0[j];
                _Float16 w0h = (_Float16)w0;
                Bhi[0][kc][j] = w0h;
                Blo[0][kc][j] = (_Float16)(w0 - (float)w0h);
                float w1 = p1[j];
                _Float16 w1h = (_Float16)w1;
                Bhi[1][kc][j] = w1h;
                Blo[1][kc][j] = (_Float16)(w1 - (float)w1h);
            }
        }
    }
    // logits B-tile (Wout rows as cols), K-split: wave0 kc 0-1, wave1 kc 2-3
    half8 BLhi[2], BLlo[2];
    {
        #pragma unroll
        for (int c = 0; c < 2; c++)
            #pragma unroll
            for (int j = 0; j < 8; j++) { BLhi[c][j] = (_Float16)0; BLlo[c][j] = (_Float16)0; }
        if (wv < 2 && mrow < OUT) {
            #pragma unroll
            for (int c = 0; c < 2; c++) {
                const int kb = (wv * 2 + c) * 32 + quad * 8;
                const float* p = Wout + (size_t)mrow * HID + kb;
                #pragma unroll
                for (int j = 0; j < 8; j++) {
                    float w = p[j];
                    _Float16 wh = (_Float16)w;
                    BLhi[c][j] = wh;
                    BLlo[c][j] = (_Float16)(w - (float)wh);
                }
            }
        }
    }

    // ---- LDS setup ----
    for (int idx = t; idx < OUT * NG; idx += NT) {
        int x = idx >> 9, g = idx & (NG - 1);
        wih_eff[idx] = Wih[g * OUT + x] + bih[g] + bhh[g];
    }
    if (t < 8) bout_lds[t] = (t < OUT) ? bout[t] : 0.0f;
    if (t == 0) { xsel_sh = OUT - 1; tf_byte_mode = 0; }
    for (int s = t; s < MAXLEN; s += NT) {
        const float* row = tonehot + (size_t)(s + 1) * OUT;
        int idx = 0;
        #pragma unroll
        for (int j = 0; j < OUT; j++) if (row[j] > 0.5f) idx = j;
        tgt8[s] = (unsigned char)idx;
    }
    __syncthreads();
    {   // tf_mask layout detection (int8 bool vs int32) — proven R1-R13
        const unsigned char* tb = (const unsigned char*)tf_raw;
        int mis = 0;
        for (int p = t; p < MAXLEN; p += NT)
            if ((p & 3) && tb[p]) mis = 1;
        if (mis) atomicOr(&tf_byte_mode, 1);
    }
    // ---- state init ----
    float c_reg = 0.f, hv = 0.f;
    if (t < HID) {
        hv    = h0[b * HID + t];
        c_reg = c0[b * HID + t];
        _Float16 hh = (_Float16)hv;
        h16s[0][t] = hh;
        h16s[1][t] = (_Float16)(hv - (float)hh);
    }
    __syncthreads();
    if (tf_byte_mode) {
        const unsigned char* tb = (const unsigned char*)tf_raw;
        for (int s = t; s < MAXLEN; s += NT) tf8[s] = (tb[s] != 0);
    } else {
        const int* ti = (const int*)tf_raw;
        for (int s = t; s < MAXLEN; s += NT) tf8[s] = (ti[s] != 0);
    }
    __syncthreads();

    float* outlp = out + (size_t)b * MAXLEN * OUT;

    for (int s = 0; s < MAXLEN; s++) {
        // ---- MFMA phase: gates(s) + logits(s-1), A rows all = h ----
        float4v acc0 = {0.f, 0.f, 0.f, 0.f};
        float4v acc1 = {0.f, 0.f, 0.f, 0.f};
        float4v lacc = {0.f, 0.f, 0.f, 0.f};
        #pragma unroll
        for (int kc = 0; kc < 4; kc++) {
            const half8 ahi = *(const half8*)&h16s[0][kc * 32 + quad * 8];
            const half8 alo = *(const half8*)&h16s[1][kc * 32 + quad * 8];
            acc0 = __builtin_amdgcn_mfma_f32_16x16x32_f16(ahi, Bhi[0][kc], acc0, 0, 0, 0);
            acc0 = __builtin_amdgcn_mfma_f32_16x16x32_f16(ahi, Blo[0][kc], acc0, 0, 0, 0);
            acc0 = __builtin_amdgcn_mfma_f32_16x16x32_f16(alo, Bhi[0][kc], acc0, 0, 0, 0);
            acc1 = __builtin_amdgcn_mfma_f32_16x16x32_f16(ahi, Bhi[1][kc], acc1, 0, 0, 0);
            acc1 = __builtin_amdgcn_mfma_f32_16x16x32_f16(ahi, Blo[1][kc], acc1, 0, 0, 0);
            acc1 = __builtin_amdgcn_mfma_f32_16x16x32_f16(alo, Bhi[1][kc], acc1, 0, 0, 0);
            if (wv < 2 && (kc >> 1) == wv) {
                const int c = kc & 1;
                lacc = __builtin_amdgcn_mfma_f32_16x16x32_f16(ahi, BLhi[c], lacc, 0, 0, 0);
                lacc = __builtin_amdgcn_mfma_f32_16x16x32_f16(ahi, BLlo[c], lacc, 0, 0, 0);
                lacc = __builtin_amdgcn_mfma_f32_16x16x32_f16(alo, BLhi[c], lacc, 0, 0, 0);
            }
        }
        // every D row is identical -> quad 0, reg 0 extracts (conflict-free)
        if (quad == 0) {
            gates_lds[wv * 32 + mrow]      = acc0[0];
            gates_lds[wv * 32 + 16 + mrow] = acc1[0];
        }
        if (wv < 2 && quad == 0 && mrow < 8) lp[wv][mrow] = lacc[0];
        __syncthreads();   // A: gates + logit partials ready

        // ---- argmax + xsel (single thread; ~30 cyc) ----
        if (s > 0 && t == 0) {
            float lg[OUT];
            #pragma unroll
            for (int j = 0; j < OUT; j++) lg[j] = lp[0][j] + lp[1][j] + bout_lds[j];
            float bv = lg[0]; int bi = 0;
            #pragma unroll
            for (int j = 1; j < OUT; j++) if (lg[j] > bv) { bv = lg[j]; bi = j; }
            xsel_sh = tf8[s - 1] ? (int)tgt8[s - 1] : bi;
            const int slot = (s - 1) & (LOGBUF - 1);
            #pragma unroll
            for (int j = 0; j < OUT; j++) ring[slot][j] = lg[j];
        }
        __syncthreads();   // A2: xsel + ring slot ready

        // ---- pointwise (t<128) || deferred log-softmax flush (t in 512..767) ----
        if (t < HID) {
            const int xo = xsel_sh * NG;
            float ri = gates_lds[t]           + wih_eff[xo + t];
            float rf = gates_lds[HID + t]     + wih_eff[xo + HID + t];
            float rg = gates_lds[2 * HID + t] + wih_eff[xo + 2 * HID + t];
            float ro = gates_lds[3 * HID + t] + wih_eff[xo + 3 * HID + t];
            float cn = sigm_(rf) * c_reg + sigm_(ri) * tanh_(rg);
            c_reg = cn;
            hv = sigm_(ro) * tanh_(cn);
            _Float16 hh = (_Float16)hv;
            h16s[0][t] = hh;
            h16s[1][t] = (_Float16)(hv - (float)hh);
        } else if ((s & (LOGBUF - 1)) == 0 && s > 0 && t >= 512 && t < 512 + LOGBUF) {
            const int st = t - 512;
            const int base = s - LOGBUF;
            float v[OUT];
            #pragma unroll
            for (int j = 0; j < OUT; j++) v[j] = ring[st][j];
            float mx = v[0];
            #pragma unroll
            for (int j = 1; j < OUT; j++) mx = fmaxf(mx, v[j]);
            float sum = 0.f;
            #pragma unroll
            for (int j = 0; j < OUT; j++) sum += __expf(v[j] - mx);
            const float lse = mx + __logf(sum);
            float* dst = outlp + (size_t)(base + st) * OUT;
            #pragma unroll
            for (int j = 0; j < OUT; j++) dst[j] = v[j] - lse;
        }
        __syncthreads();   // C: h(s+1) staged in h16s
    }

    // ---- epilogue: logits for step 2047 from final h ----
    if (wv < 2) {
        float4v lacc = {0.f, 0.f, 0.f, 0.f};
        #pragma unroll
        for (int c = 0; c < 2; c++) {
            const int kc = wv * 2 + c;
            const half8 ahi = *(const half8*)&h16s[0][kc * 32 + quad * 8];
            const half8 alo = *(const half8*)&h16s[1][kc * 32 + quad * 8];
            lacc = __builtin_amdgcn_mfma_f32_16x16x32_f16(ahi, BLhi[c], lacc, 0, 0, 0);
            lacc = __builtin_amdgcn_mfma_f32_16x16x32_f16(ahi, BLlo[c], lacc, 0, 0, 0);
            lacc = __builtin_amdgcn_mfma_f32_16x16x32_f16(alo, BLhi[c], lacc, 0, 0, 0);
        }
        if (quad == 0 && mrow < 8) lp[wv][mrow] = lacc[0];
    }
    __syncthreads();
    if (t == 0) {
        const int slot = (MAXLEN - 1) & (LOGBUF - 1);
        #pragma unroll
        for (int j = 0; j < OUT; j++) ring[slot][j] = lp[0][j] + lp[1][j] + bout_lds[j];
    }
    __syncthreads();
    if (t < LOGBUF) {   // final flush: steps 1792..2047
        const int base = MAXLEN - LOGBUF;
        float v[OUT];
        #pragma unroll
        for (int j = 0; j < OUT; j++) v[j] = ring[t][j];
        float mx = v[0];
        #pragma unroll
        for (int j = 1; j < OUT; j++) mx = fmaxf(mx, v[j]);
        float sum = 0.f;
        #pragma unroll
        for (int j = 0; j < OUT; j++) sum += __expf(v[j] - mx);
        const float lse = mx + __logf(sum);
        float* dst = outlp + (size_t)(base + t) * OUT;
        #pragma unroll
        for (int j = 0; j < OUT; j++) dst[j] = v[j] - lse;
    }
    if (t < HID) {
        out[OFF_STATE + b * HID + t] = hv;                        // hT
        out[OFF_STATE + BATCH * HID + b * HID + t] = c_reg;       // cT
    }
}

extern "C" void kernel_launch(void* const* d_in, const int* in_sizes, int n_in,
                              void* d_out, int out_size, void* d_ws, size_t ws_size,
                              hipStream_t stream) {
    const float* h0    = (const float*)d_in[0];
    const float* c0    = (const float*)d_in[1];
    const float* toh   = (const float*)d_in[2];
    const void*  tfm   = (const void*) d_in[3];
    const float* Wih   = (const float*)d_in[4];
    const float* Whh   = (const float*)d_in[5];
    const float* bih   = (const float*)d_in[6];
    const float* bhh   = (const float*)d_in[7];
    const float* Wout  = (const float*)d_in[8];
    const float* bout  = (const float*)d_in[9];
    float* out = (float*)d_out;

    decoder_rnn_kernel<<<dim3(BATCH), dim3(NT), 0, stream>>>(
        h0, c0, toh, tfm, Wih, Whh, bih, bhh, Wout, bout, out);
}